// Round 2
// baseline (407.442 us; speedup 1.0000x reference)
//
#include <hip/hip_runtime.h>
#include <math.h>

#define B_    4
#define L_    4092
#define H_    8
#define DM    512
#define WS_   12
#define NW    681
#define NC    682            // 6-row output chunks per (b,h); L = 6*682
#define EPS_  1e-5f
#define Z_ELEMS (B_*L_*DM)   // 8,380,416

typedef unsigned short u16;

__device__ __forceinline__ u16 f2bf(float f) {
    union { float f; unsigned u; } x; x.f = f;
    unsigned u = x.u;
    return (u16)((u + 0x7FFFu + ((u >> 16) & 1u)) >> 16);
}
__device__ __forceinline__ float bf2f(u16 h) {
    union { unsigned u; float f; } x; x.u = ((unsigned)h) << 16; return x.f;
}

// ---------------------------------------------------------------------------
// K1: pure-fp32 VALU projection GEMM. Rows r=(b*H+h)*L+l, 130,944 = 8184
// blocks x 16 rows. Block: stage X[16][64] in LDS; wave w owns rows w*4..+3;
// lane = output column e; W row e streamed from global (16 KB, L1-resident).
// Q,K stored fp32 (EXACT, no bf16 anywhere in the score chain); V stored
// bf16 (error contribution to z bounded ~6e-3, 17x under threshold).
// ---------------------------------------------------------------------------
__global__ __launch_bounds__(256) void proj_kernel(
    const float* __restrict__ q, const float* __restrict__ k, const float* __restrict__ v,
    const float* __restrict__ Wq, const float* __restrict__ Wk, const float* __restrict__ Wv,
    float* __restrict__ Qf, float* __restrict__ Kf, u16* __restrict__ Vh)
{
    __shared__ alignas(16) float Xl[16][64];

    const int tensor = blockIdx.y;
    const float* __restrict__ X = (tensor == 0) ? q  : (tensor == 1) ? k  : v;
    const float* __restrict__ W = (tensor == 0) ? Wq : (tensor == 1) ? Wk : Wv;

    const int t = threadIdx.x, lane = t & 63, w = t >> 6;
    const int rbase = blockIdx.x * 16;

    // stage 16 rows of X: thread t loads row t>>4, float4 at (t&15)*4
    {
        const int i = t >> 4, q4 = (t & 15) * 4;
        const int r = rbase + i;
        const int bh = r / L_, l = r - bh * L_;
        const int b = bh >> 3, h = bh & 7;
        *(float4*)&Xl[i][q4] =
            *(const float4*)(X + (((size_t)b * L_ + l) * H_ + h) * 64 + q4);
    }
    __syncthreads();

    float acc0 = 0.f, acc1 = 0.f, acc2 = 0.f, acc3 = 0.f;
    const int r0 = w * 4;
    const float* Wrow = W + lane * 64;
    #pragma unroll
    for (int d4 = 0; d4 < 16; ++d4) {
        const float4 wv = *(const float4*)(Wrow + d4 * 4);
        const float4 x0 = *(const float4*)&Xl[r0 + 0][d4 * 4];
        const float4 x1 = *(const float4*)&Xl[r0 + 1][d4 * 4];
        const float4 x2 = *(const float4*)&Xl[r0 + 2][d4 * 4];
        const float4 x3 = *(const float4*)&Xl[r0 + 3][d4 * 4];
        acc0 += x0.x*wv.x + x0.y*wv.y + x0.z*wv.z + x0.w*wv.w;
        acc1 += x1.x*wv.x + x1.y*wv.y + x1.z*wv.z + x1.w*wv.w;
        acc2 += x2.x*wv.x + x2.y*wv.y + x2.z*wv.z + x2.w*wv.w;
        acc3 += x3.x*wv.x + x3.y*wv.y + x3.z*wv.z + x3.w*wv.w;
    }

    const size_t gr = (size_t)(rbase + r0) * 64 + lane;
    if (tensor == 0) {
        Qf[gr]        = acc0; Qf[gr + 64]  = acc1;
        Qf[gr + 128]  = acc2; Qf[gr + 192] = acc3;
    } else if (tensor == 1) {
        Kf[gr]        = acc0; Kf[gr + 64]  = acc1;
        Kf[gr + 128]  = acc2; Kf[gr + 192] = acc3;
    } else {
        Vh[gr]        = f2bf(acc0); Vh[gr + 64]  = f2bf(acc1);
        Vh[gr + 128]  = f2bf(acc2); Vh[gr + 192] = f2bf(acc3);
    }
}

// ---------------------------------------------------------------------------
// K2: all-fp32 VALU fused window attention + overlap-add + residual + LN.
// Block = (chunk c, batch b), 512 threads, wave = head h.
// Lane (qq = lane>>2, ks = lane&3): owns score row qq, d-segment [ks*16,+16).
// Partial dots reduced over the 4 ks-lanes (2 shfl_xor); softmax is fully
// lane-local (each lane holds its entire 12-wide row). Window B remaps lanes
// qq<6 to rows qq+6 of window c-1 (same global Q row as window A -> Q regs
// reused; A/B overlap-average combined in-register). Only 2 barriers.
// ---------------------------------------------------------------------------
__global__ __launch_bounds__(512) void attn_ln_kernel(
    const float* __restrict__ Qf, const float* __restrict__ Kf, const u16* __restrict__ Vh,
    const float* __restrict__ qres, const float* __restrict__ gamma,
    const float* __restrict__ beta, float* __restrict__ attn, float* __restrict__ z)
{
    __shared__ alignas(16) float Vsf[8][18][64];   // 36.9 KB
    __shared__ alignas(16) float Xs[6][512];       // 12.3 KB

    const int c = blockIdx.x, b = blockIdx.y;
    const int t = threadIdx.x, lane = t & 63, h = t >> 6;
    const int qq = lane >> 2, ks = lane & 3;
    const int bh = b * 8 + h;

    // --- stage V rows lbase..lbase+17 (bf16 -> fp32), bounds-checked ---
    const int lbase = c * 6 - 6;
    for (int i = t; i < 2304; i += 512) {            // 2304 = 8*18*4 float4s
        const int hh  = i / 288;
        const int rem = i - hh * 288;
        const int rr  = rem >> 4;
        const int cc  = (rem & 15) * 4;
        const int l = lbase + rr;
        if (l >= 0 && l < L_) {
            ushort4 u4 = *(const ushort4*)(Vh + ((size_t)(b * 8 + hh) * L_ + l) * 64 + cc);
            float4 f4;
            f4.x = bf2f(u4.x); f4.y = bf2f(u4.y); f4.z = bf2f(u4.z); f4.w = bf2f(u4.w);
            *(float4*)&Vsf[hh][rr][cc] = f4;
        }
    }
    __syncthreads();

    const bool hasA = (c < NW), hasB = (c > 0);     // block-uniform
    const float* Qb = Qf + (size_t)bh * L_ * 64;
    const float* Kb = Kf + (size_t)bh * L_ * 64;

    // Q segment for global row c*6+qq (valid: qq<6 always; qq<12 when hasA)
    float4 qs0, qs1, qs2, qs3;
    const bool qload = (qq < 6) || (hasA && qq < 12);
    if (qload) {
        const float* qp = Qb + (size_t)(c * 6 + qq) * 64 + ks * 16;
        qs0 = *(const float4*)(qp);     qs1 = *(const float4*)(qp + 4);
        qs2 = *(const float4*)(qp + 8); qs3 = *(const float4*)(qp + 12);
    } else {
        qs0 = qs1 = qs2 = qs3 = make_float4(0.f, 0.f, 0.f, 0.f);
    }

    float4 oA[4];
    float4 xo[4];

    // ================= window A (index c): V offset 6 =================
    if (hasA) {
        float p[12];
        #pragma unroll
        for (int kk = 0; kk < 12; ++kk) p[kk] = 0.f;
        if (qq < 12) {
            #pragma unroll
            for (int kk = 0; kk < 12; ++kk) {
                const float* kp = Kb + (size_t)(c * 6 + kk) * 64 + ks * 16;
                const float4 k0 = *(const float4*)(kp);
                const float4 k1 = *(const float4*)(kp + 4);
                const float4 k2 = *(const float4*)(kp + 8);
                const float4 k3 = *(const float4*)(kp + 12);
                p[kk] = qs0.x*k0.x + qs0.y*k0.y + qs0.z*k0.z + qs0.w*k0.w
                      + qs1.x*k1.x + qs1.y*k1.y + qs1.z*k1.z + qs1.w*k1.w
                      + qs2.x*k2.x + qs2.y*k2.y + qs2.z*k2.z + qs2.w*k2.w
                      + qs3.x*k3.x + qs3.y*k3.y + qs3.z*k3.z + qs3.w*k3.w;
            }
        }
        // reduce partial dots over the 4 ks-lanes of this row
        #pragma unroll
        for (int kk = 0; kk < 12; ++kk) {
            p[kk] += __shfl_xor(p[kk], 1);
            p[kk] += __shfl_xor(p[kk], 2);
        }
        // lane-local softmax over the 12-wide row (scale 1/8 inside exp)
        float mx = p[0];
        #pragma unroll
        for (int kk = 1; kk < 12; ++kk) mx = fmaxf(mx, p[kk]);
        float sum = 0.f;
        #pragma unroll
        for (int kk = 0; kk < 12; ++kk) { p[kk] = __expf((p[kk] - mx) * 0.125f); sum += p[kk]; }
        const float inv = 1.0f / sum;
        #pragma unroll
        for (int kk = 0; kk < 12; ++kk) p[kk] *= inv;

        // attn output: window c, all 12 rows (written once, by this block)
        if (ks == 0 && qq < 12) {
            float* ao = attn + ((size_t)bh * NW + c) * 144 + qq * 12;
            float4 a0; a0.x = p[0]; a0.y = p[1];  a0.z = p[2];  a0.w = p[3];
            float4 a1; a1.x = p[4]; a1.y = p[5];  a1.z = p[6];  a1.w = p[7];
            float4 a2; a2.x = p[8]; a2.y = p[9];  a2.z = p[10]; a2.w = p[11];
            *(float4*)(ao)     = a0;
            *(float4*)(ao + 4) = a1;
            *(float4*)(ao + 8) = a2;
        }

        // PV: only rows 0..5 feed this chunk
        if (qq < 6) {
            #pragma unroll
            for (int j4 = 0; j4 < 4; ++j4) oA[j4] = make_float4(0.f, 0.f, 0.f, 0.f);
            #pragma unroll
            for (int kk = 0; kk < 12; ++kk) {
                const float pv = p[kk];
                #pragma unroll
                for (int j4 = 0; j4 < 4; ++j4) {
                    const float4 vv = *(const float4*)&Vsf[h][6 + kk][ks * 16 + j4 * 4];
                    oA[j4].x += pv * vv.x; oA[j4].y += pv * vv.y;
                    oA[j4].z += pv * vv.z; oA[j4].w += pv * vv.w;
                }
            }
        }
    }

    // ====== window B (index c-1): lanes qq<6 act as rows qq+6; V offset 0 ======
    if (hasB) {
        float pb[12];
        #pragma unroll
        for (int kk = 0; kk < 12; ++kk) pb[kk] = 0.f;
        if (qq < 6) {
            // row (c-1)*6 + (qq+6) == c*6+qq -> same Q segment as window A
            #pragma unroll
            for (int kk = 0; kk < 12; ++kk) {
                const float* kp = Kb + (size_t)((c - 1) * 6 + kk) * 64 + ks * 16;
                const float4 k0 = *(const float4*)(kp);
                const float4 k1 = *(const float4*)(kp + 4);
                const float4 k2 = *(const float4*)(kp + 8);
                const float4 k3 = *(const float4*)(kp + 12);
                pb[kk] = qs0.x*k0.x + qs0.y*k0.y + qs0.z*k0.z + qs0.w*k0.w
                       + qs1.x*k1.x + qs1.y*k1.y + qs1.z*k1.z + qs1.w*k1.w
                       + qs2.x*k2.x + qs2.y*k2.y + qs2.z*k2.z + qs2.w*k2.w
                       + qs3.x*k3.x + qs3.y*k3.y + qs3.z*k3.z + qs3.w*k3.w;
            }
        }
        #pragma unroll
        for (int kk = 0; kk < 12; ++kk) {
            pb[kk] += __shfl_xor(pb[kk], 1);
            pb[kk] += __shfl_xor(pb[kk], 2);
        }
        if (qq < 6) {
            float mx = pb[0];
            #pragma unroll
            for (int kk = 1; kk < 12; ++kk) mx = fmaxf(mx, pb[kk]);
            float sum = 0.f;
            #pragma unroll
            for (int kk = 0; kk < 12; ++kk) { pb[kk] = __expf((pb[kk] - mx) * 0.125f); sum += pb[kk]; }
            const float inv = 1.0f / sum;
            #pragma unroll
            for (int kk = 0; kk < 12; ++kk) pb[kk] *= inv;

            float4 oB[4];
            #pragma unroll
            for (int j4 = 0; j4 < 4; ++j4) oB[j4] = make_float4(0.f, 0.f, 0.f, 0.f);
            #pragma unroll
            for (int kk = 0; kk < 12; ++kk) {
                const float pv = pb[kk];
                #pragma unroll
                for (int j4 = 0; j4 < 4; ++j4) {
                    const float4 vv = *(const float4*)&Vsf[h][kk][ks * 16 + j4 * 4];
                    oB[j4].x += pv * vv.x; oB[j4].y += pv * vv.y;
                    oB[j4].z += pv * vv.z; oB[j4].w += pv * vv.w;
                }
            }
            if (hasA) {
                #pragma unroll
                for (int j4 = 0; j4 < 4; ++j4) {
                    xo[j4].x = 0.5f * (oA[j4].x + oB[j4].x);
                    xo[j4].y = 0.5f * (oA[j4].y + oB[j4].y);
                    xo[j4].z = 0.5f * (oA[j4].z + oB[j4].z);
                    xo[j4].w = 0.5f * (oA[j4].w + oB[j4].w);
                }
            } else {
                #pragma unroll
                for (int j4 = 0; j4 < 4; ++j4) xo[j4] = oB[j4];
            }
        }
    } else {
        if (qq < 6) {
            #pragma unroll
            for (int j4 = 0; j4 < 4; ++j4) xo[j4] = oA[j4];
        }
    }

    // stash combined chunk rows 0..5 for the cross-head LN
    if (qq < 6) {
        #pragma unroll
        for (int j4 = 0; j4 < 4; ++j4)
            *(float4*)&Xs[qq][h * 64 + ks * 16 + j4 * 4] = xo[j4];
    }
    __syncthreads();

    // --- LN: wave h (<6) handles chunk row h; lane covers 8 cols ---
    if (h < 6) {
        const int l = c * 6 + h;
        const int cc = lane * 8;
        float4 xa = *(const float4*)&Xs[h][cc];
        float4 xb = *(const float4*)&Xs[h][cc + 4];
        const float* qr = qres + ((size_t)b * L_ + l) * DM + cc;
        const float4 ra  = *(const float4*)qr;
        const float4 rb2 = *(const float4*)(qr + 4);
        xa.x += ra.x;  xa.y += ra.y;  xa.z += ra.z;  xa.w += ra.w;
        xb.x += rb2.x; xb.y += rb2.y; xb.z += rb2.z; xb.w += rb2.w;

        float s1 = xa.x + xa.y + xa.z + xa.w + xb.x + xb.y + xb.z + xb.w;
        float s2 = xa.x*xa.x + xa.y*xa.y + xa.z*xa.z + xa.w*xa.w
                 + xb.x*xb.x + xb.y*xb.y + xb.z*xb.z + xb.w*xb.w;
        #pragma unroll
        for (int off = 1; off < 64; off <<= 1) {
            s1 += __shfl_xor(s1, off, 64);
            s2 += __shfl_xor(s2, off, 64);
        }
        const float mu  = s1 * (1.0f / 512.0f);
        const float var = s2 * (1.0f / 512.0f) - mu * mu;
        const float inv = 1.0f / sqrtf(var + EPS_);

        const float4 ga = *(const float4*)(gamma + cc);
        const float4 gb = *(const float4*)(gamma + cc + 4);
        const float4 ba = *(const float4*)(beta + cc);
        const float4 bb = *(const float4*)(beta + cc + 4);
        float4 oa, ob;
        oa.x = (xa.x - mu) * inv * ga.x + ba.x;
        oa.y = (xa.y - mu) * inv * ga.y + ba.y;
        oa.z = (xa.z - mu) * inv * ga.z + ba.z;
        oa.w = (xa.w - mu) * inv * ga.w + ba.w;
        ob.x = (xb.x - mu) * inv * gb.x + bb.x;
        ob.y = (xb.y - mu) * inv * gb.y + bb.y;
        ob.z = (xb.z - mu) * inv * gb.z + bb.z;
        ob.w = (xb.w - mu) * inv * gb.w + bb.w;
        float* zp = z + ((size_t)b * L_ + l) * DM + cc;
        *(float4*)zp = oa;
        *(float4*)(zp + 4) = ob;
    }
}

extern "C" void kernel_launch(void* const* d_in, const int* in_sizes, int n_in,
                              void* d_out, int out_size, void* d_ws, size_t ws_size,
                              hipStream_t stream) {
    const float* q     = (const float*)d_in[0];
    const float* k     = (const float*)d_in[1];
    const float* v     = (const float*)d_in[2];
    const float* Wq    = (const float*)d_in[3];
    const float* Wk    = (const float*)d_in[4];
    const float* Wv    = (const float*)d_in[5];
    const float* gamma = (const float*)d_in[6];
    const float* beta  = (const float*)d_in[7];

    float* z    = (float*)d_out;
    float* attn = (float*)d_out + Z_ELEMS;

    // Workspace: Qf fp32 (33.5 MB) + Kf fp32 (33.5 MB) + Vh bf16 (16.8 MB)
    // = 83.8 MB, identical to the round-0 footprint (proven mapped).
    const size_t plane = (size_t)B_ * H_ * L_ * 64;   // 8,380,416 elements
    float* Qf = (float*)d_ws;
    float* Kf = Qf + plane;
    u16*  Vh  = (u16*)(Kf + plane);

    proj_kernel<<<dim3(8184, 3, 1), 256, 0, stream>>>(q, k, v, Wq, Wk, Wv, Qf, Kf, Vh);
    attn_ln_kernel<<<dim3(NC, B_), 512, 0, stream>>>(Qf, Kf, Vh, q, gamma, beta, attn, z);
}

// Round 3
// 247.494 us; speedup vs baseline: 1.6463x; 1.6463x over previous
//
#include <hip/hip_runtime.h>
#include <math.h>

#define B_    4
#define L_    4092
#define H_    8
#define DM    512
#define WS_   12
#define NW    681
#define NC    682            // 6-row output chunks per (b,h); L = 6*682
#define EPS_  1e-5f
#define Z_ELEMS (B_*L_*DM)   // 8,380,416
#define NQUAD 32736          // 130,944 rows / 4

typedef unsigned short u16;

__device__ __forceinline__ u16 f2bf(float f) {
    union { float f; unsigned u; } x; x.f = f;
    unsigned u = x.u;
    return (u16)((u + 0x7FFFu + ((u >> 16) & 1u)) >> 16);
}
__device__ __forceinline__ float bf2f(u16 h) {
    union { unsigned u; float f; } x; x.u = ((unsigned)h) << 16; return x.f;
}

// ---------------------------------------------------------------------------
// K1: pure-fp32 VALU projection GEMM, persistent-wave version.
// Round-2 rocprof: 192 µs, VALUBusy 31%, HBM 3% -> L1-transaction-bound on
// per-block re-loads of W (64 strided cache lines per instr, 16x per thread,
// x8184 blocks). Fix: W row `lane` lives in 64 VGPRs, loaded ONCE per wave;
// waves grid-stride over 4-row quads; X staged through wave-private LDS
// (broadcast reads, NO barriers). Q,K stored fp32 (exact score chain);
// V stored bf16 (error contribution ~6e-3, far under threshold).
// ---------------------------------------------------------------------------
__global__ __launch_bounds__(256) void proj_kernel(
    const float* __restrict__ q, const float* __restrict__ k, const float* __restrict__ v,
    const float* __restrict__ Wq, const float* __restrict__ Wk, const float* __restrict__ Wv,
    float* __restrict__ Qf, float* __restrict__ Kf, u16* __restrict__ Vh)
{
    const int tensor = blockIdx.y;
    const float* __restrict__ X = (tensor == 0) ? q  : (tensor == 1) ? k  : v;
    const float* __restrict__ W = (tensor == 0) ? Wq : (tensor == 1) ? Wk : Wv;
    float* __restrict__ Yf      = (tensor == 0) ? Qf : Kf;
    const bool isV = (tensor == 2);

    const int t = threadIdx.x, lane = t & 63, wv = t >> 6;

    // W row `lane` -> 64 VGPRs (uncoalesced, but ONCE per wave)
    float4 wr[16];
    #pragma unroll
    for (int j = 0; j < 16; ++j)
        wr[j] = *(const float4*)(W + lane * 64 + j * 4);

    __shared__ alignas(16) float Xw[4][4][64];   // wave-private 1 KB slices

    const int li = lane >> 4;          // which quad-row this lane stages
    const int lc = (lane & 15) * 4;    // col

    const int waveId = blockIdx.x * 4 + wv;      // 0..2047
    for (int qd = waveId; qd < NQUAD; qd += 2048) {
        const int rbase = qd * 4;
        const int r = rbase + li;                // quads never cross bh (4092%4==0)
        const int bh = r / L_;
        const int l = r - bh * L_;
        const int b = bh >> 3, h = bh & 7;
        const float4 xf = *(const float4*)(X + (((size_t)b * L_ + l) * H_ + h) * 64 + lc);
        *(float4*)&Xw[wv][li][lc] = xf;
        // wave-private handoff: same-wave DS ops are in-order; compiler
        // inserts the lgkmcnt. No __syncthreads anywhere in this kernel.

        float acc0 = 0.f, acc1 = 0.f, acc2 = 0.f, acc3 = 0.f;
        #pragma unroll
        for (int d4 = 0; d4 < 16; ++d4) {
            const float4 w4 = wr[d4];
            const float4 x0 = *(const float4*)&Xw[wv][0][d4 * 4];  // broadcast reads
            const float4 x1 = *(const float4*)&Xw[wv][1][d4 * 4];
            const float4 x2 = *(const float4*)&Xw[wv][2][d4 * 4];
            const float4 x3 = *(const float4*)&Xw[wv][3][d4 * 4];
            acc0 += x0.x*w4.x + x0.y*w4.y + x0.z*w4.z + x0.w*w4.w;
            acc1 += x1.x*w4.x + x1.y*w4.y + x1.z*w4.z + x1.w*w4.w;
            acc2 += x2.x*w4.x + x2.y*w4.y + x2.z*w4.z + x2.w*w4.w;
            acc3 += x3.x*w4.x + x3.y*w4.y + x3.z*w4.z + x3.w*w4.w;
        }

        const size_t orow = (size_t)rbase * 64 + lane;
        if (!isV) {
            Yf[orow]       = acc0;
            Yf[orow + 64]  = acc1;
            Yf[orow + 128] = acc2;
            Yf[orow + 192] = acc3;
        } else {
            Vh[orow]       = f2bf(acc0);
            Vh[orow + 64]  = f2bf(acc1);
            Vh[orow + 128] = f2bf(acc2);
            Vh[orow + 192] = f2bf(acc3);
        }
    }
}

// ---------------------------------------------------------------------------
// K2: fused window attention + overlap-add + residual + LayerNorm.
// Round-2 diagnosis: latency-bound on ~100 dependent global K loads per wave
// (16x redundant across qq-groups). Fix: stage the 18-row K tile in LDS fp32
// alongside V; dots are broadcast ds_read_b128 (16 lanes same addr = free).
// Unified 18-row dot pass (windows A/B share 6 dot values) + fused PV pass
// with combined weights. Xs (LN exchange) aliases the dead K region after a
// barrier -> LDS 73.7 KB, 2 blocks/CU. OOB tile rows zero-filled.
// ---------------------------------------------------------------------------
__global__ __launch_bounds__(512, 4) void attn_ln_kernel(
    const float* __restrict__ Qf, const float* __restrict__ Kf, const u16* __restrict__ Vh,
    const float* __restrict__ qres, const float* __restrict__ gamma,
    const float* __restrict__ beta, float* __restrict__ attn, float* __restrict__ z)
{
    __shared__ alignas(16) float Ks[8][18][64];   // 36.9 KB (later aliased as Xs)
    __shared__ alignas(16) float Vsf[8][18][64];  // 36.9 KB

    const int c = blockIdx.x, b = blockIdx.y;
    const int t = threadIdx.x, lane = t & 63, h = t >> 6;
    const int qq = lane >> 2, ks = lane & 3;
    const int bh = b * 8 + h;
    const int lbase = c * 6 - 6;

    // --- stage K (fp32) + V (bf16->fp32), zero-filling OOB rows ---
    for (int i = t; i < 2304; i += 512) {          // 2304 = 8 heads * 18 rows * 16 float4
        const int hh  = i / 288;
        const int rem = i - hh * 288;
        const int rr  = rem >> 4;
        const int cc  = (rem & 15) * 4;
        const int l = lbase + rr;
        float4 kf4 = make_float4(0.f, 0.f, 0.f, 0.f);
        float4 vf4 = make_float4(0.f, 0.f, 0.f, 0.f);
        if (l >= 0 && l < L_) {
            const size_t base = ((size_t)(b * 8 + hh) * L_ + l) * 64 + cc;
            kf4 = *(const float4*)(Kf + base);
            const ushort4 u4 = *(const ushort4*)(Vh + base);
            vf4.x = bf2f(u4.x); vf4.y = bf2f(u4.y); vf4.z = bf2f(u4.z); vf4.w = bf2f(u4.w);
        }
        *(float4*)&Ks[hh][rr][cc]  = kf4;
        *(float4*)&Vsf[hh][rr][cc] = vf4;
    }
    __syncthreads();

    const bool hasA = (c < NW), hasB = (c > 0);     // block-uniform
    const float scale = (hasA && hasB) ? 0.5f : 1.0f;

    // Q segment for global row c*6+qq (zeros on invalid lanes -> s == 0, finite)
    float4 qs0, qs1, qs2, qs3;
    const int qmax = hasA ? 12 : 6;
    if (qq < qmax) {
        const float* qp = Qf + ((size_t)bh * L_ + (c * 6 + qq)) * 64 + ks * 16;
        qs0 = *(const float4*)(qp);     qs1 = *(const float4*)(qp + 4);
        qs2 = *(const float4*)(qp + 8); qs3 = *(const float4*)(qp + 12);
    } else {
        qs0 = qs1 = qs2 = qs3 = make_float4(0.f, 0.f, 0.f, 0.f);
    }

    // --- unified dot pass: Q row (c*6+qq) vs all 18 staged K rows ---
    float s[18];
    #pragma unroll
    for (int kt = 0; kt < 18; ++kt) {
        const float* kp = &Ks[h][kt][ks * 16];
        const float4 k0 = *(const float4*)(kp);
        const float4 k1 = *(const float4*)(kp + 4);
        const float4 k2 = *(const float4*)(kp + 8);
        const float4 k3 = *(const float4*)(kp + 12);
        s[kt] = qs0.x*k0.x + qs0.y*k0.y + qs0.z*k0.z + qs0.w*k0.w
              + qs1.x*k1.x + qs1.y*k1.y + qs1.z*k1.z + qs1.w*k1.w
              + qs2.x*k2.x + qs2.y*k2.y + qs2.z*k2.z + qs2.w*k2.w
              + qs3.x*k3.x + qs3.y*k3.y + qs3.z*k3.z + qs3.w*k3.w;
    }
    // reduce partial dots over the 4 ks-lanes (all lanes participate)
    #pragma unroll
    for (int kt = 0; kt < 18; ++kt) {
        s[kt] += __shfl_xor(s[kt], 1);
        s[kt] += __shfl_xor(s[kt], 2);
    }

    // --- softmax A: window c, over s[6..17] ---
    float eA[12], invA = 0.f;
    if (hasA) {
        float mxA = s[6];
        #pragma unroll
        for (int j = 1; j < 12; ++j) mxA = fmaxf(mxA, s[6 + j]);
        float sumA = 0.f;
        #pragma unroll
        for (int j = 0; j < 12; ++j) { eA[j] = __expf((s[6 + j] - mxA) * 0.125f); sumA += eA[j]; }
        invA = 1.0f / sumA;
        if (ks == 0 && qq < 12) {
            float* ao = attn + ((size_t)bh * NW + c) * 144 + qq * 12;
            float4 a0, a1, a2;
            a0.x = eA[0]*invA; a0.y = eA[1]*invA;  a0.z = eA[2]*invA;  a0.w = eA[3]*invA;
            a1.x = eA[4]*invA; a1.y = eA[5]*invA;  a1.z = eA[6]*invA;  a1.w = eA[7]*invA;
            a2.x = eA[8]*invA; a2.y = eA[9]*invA;  a2.z = eA[10]*invA; a2.w = eA[11]*invA;
            *(float4*)(ao)     = a0;
            *(float4*)(ao + 4) = a1;
            *(float4*)(ao + 8) = a2;
        }
    } else {
        #pragma unroll
        for (int j = 0; j < 12; ++j) eA[j] = 0.f;
    }

    // --- softmax B: window c-1 (this Q row acts as its row qq+6), over s[0..11] ---
    float eB[12], invB = 0.f;
    if (hasB) {
        float mxB = s[0];
        #pragma unroll
        for (int j = 1; j < 12; ++j) mxB = fmaxf(mxB, s[j]);
        float sumB = 0.f;
        #pragma unroll
        for (int j = 0; j < 12; ++j) { eB[j] = __expf((s[j] - mxB) * 0.125f); sumB += eB[j]; }
        invB = 1.0f / sumB;
    } else {
        #pragma unroll
        for (int j = 0; j < 12; ++j) eB[j] = 0.f;
    }

    // --- fused PV over all 18 tile rows with combined overlap-add weights ---
    float4 xo0 = make_float4(0.f,0.f,0.f,0.f), xo1 = xo0, xo2 = xo0, xo3 = xo0;
    if (qq < 6) {
        #pragma unroll
        for (int kt = 0; kt < 18; ++kt) {
            const float wa = (kt >= 6) ? eA[kt - 6] * invA : 0.f;
            const float wb = (kt < 12) ? eB[kt] * invB : 0.f;
            const float wk = scale * (wa + wb);
            const float* vp = &Vsf[h][kt][ks * 16];
            const float4 v0 = *(const float4*)(vp);
            const float4 v1 = *(const float4*)(vp + 4);
            const float4 v2 = *(const float4*)(vp + 8);
            const float4 v3 = *(const float4*)(vp + 12);
            xo0.x += wk*v0.x; xo0.y += wk*v0.y; xo0.z += wk*v0.z; xo0.w += wk*v0.w;
            xo1.x += wk*v1.x; xo1.y += wk*v1.y; xo1.z += wk*v1.z; xo1.w += wk*v1.w;
            xo2.x += wk*v2.x; xo2.y += wk*v2.y; xo2.z += wk*v2.z; xo2.w += wk*v2.w;
            xo3.x += wk*v3.x; xo3.y += wk*v3.y; xo3.z += wk*v3.z; xo3.w += wk*v3.w;
        }
    }
    __syncthreads();                 // all Ks reads complete before aliasing

    // Xs aliases the (now dead) Ks region; stride 516 breaks bank alignment
    float* Xs = &Ks[0][0][0];
    if (qq < 6) {
        float* xp = Xs + qq * 516 + h * 64 + ks * 16;
        *(float4*)(xp)      = xo0;
        *(float4*)(xp + 4)  = xo1;
        *(float4*)(xp + 8)  = xo2;
        *(float4*)(xp + 12) = xo3;
    }
    __syncthreads();

    // --- LN: wave h (<6) handles chunk row h; lane covers 8 cols ---
    if (h < 6) {
        const int l = c * 6 + h;
        const int cc = lane * 8;
        float4 xa = *(const float4*)(Xs + h * 516 + cc);
        float4 xb = *(const float4*)(Xs + h * 516 + cc + 4);
        const float* qr = qres + ((size_t)b * L_ + l) * DM + cc;
        const float4 ra  = *(const float4*)qr;
        const float4 rb2 = *(const float4*)(qr + 4);
        xa.x += ra.x;  xa.y += ra.y;  xa.z += ra.z;  xa.w += ra.w;
        xb.x += rb2.x; xb.y += rb2.y; xb.z += rb2.z; xb.w += rb2.w;

        float s1 = xa.x + xa.y + xa.z + xa.w + xb.x + xb.y + xb.z + xb.w;
        float s2 = xa.x*xa.x + xa.y*xa.y + xa.z*xa.z + xa.w*xa.w
                 + xb.x*xb.x + xb.y*xb.y + xb.z*xb.z + xb.w*xb.w;
        #pragma unroll
        for (int off = 1; off < 64; off <<= 1) {
            s1 += __shfl_xor(s1, off, 64);
            s2 += __shfl_xor(s2, off, 64);
        }
        const float mu  = s1 * (1.0f / 512.0f);
        const float var = s2 * (1.0f / 512.0f) - mu * mu;
        const float inv = 1.0f / sqrtf(var + EPS_);

        const float4 ga = *(const float4*)(gamma + cc);
        const float4 gb = *(const float4*)(gamma + cc + 4);
        const float4 ba = *(const float4*)(beta + cc);
        const float4 bb = *(const float4*)(beta + cc + 4);
        float4 oa, ob;
        oa.x = (xa.x - mu) * inv * ga.x + ba.x;
        oa.y = (xa.y - mu) * inv * ga.y + ba.y;
        oa.z = (xa.z - mu) * inv * ga.z + ba.z;
        oa.w = (xa.w - mu) * inv * ga.w + ba.w;
        ob.x = (xb.x - mu) * inv * gb.x + bb.x;
        ob.y = (xb.y - mu) * inv * gb.y + bb.y;
        ob.z = (xb.z - mu) * inv * gb.z + bb.z;
        ob.w = (xb.w - mu) * inv * gb.w + bb.w;
        float* zp = z + ((size_t)b * L_ + l) * DM + cc;
        *(float4*)zp = oa;
        *(float4*)(zp + 4) = ob;
    }
}

extern "C" void kernel_launch(void* const* d_in, const int* in_sizes, int n_in,
                              void* d_out, int out_size, void* d_ws, size_t ws_size,
                              hipStream_t stream) {
    const float* q     = (const float*)d_in[0];
    const float* k     = (const float*)d_in[1];
    const float* v     = (const float*)d_in[2];
    const float* Wq    = (const float*)d_in[3];
    const float* Wk    = (const float*)d_in[4];
    const float* Wv    = (const float*)d_in[5];
    const float* gamma = (const float*)d_in[6];
    const float* beta  = (const float*)d_in[7];

    float* z    = (float*)d_out;
    float* attn = (float*)d_out + Z_ELEMS;

    // Workspace: Qf fp32 (33.5 MB) + Kf fp32 (33.5 MB) + Vh bf16 (16.8 MB)
    const size_t plane = (size_t)B_ * H_ * L_ * 64;   // 8,380,416 elements
    float* Qf = (float*)d_ws;
    float* Kf = Qf + plane;
    u16*  Vh  = (u16*)(Kf + plane);

    proj_kernel<<<dim3(512, 3, 1), 256, 0, stream>>>(q, k, v, Wq, Wk, Wv, Qf, Kf, Vh);
    attn_ln_kernel<<<dim3(NC, B_), 512, 0, stream>>>(Qf, Kf, Vh, q, gamma, beta, attn, z);
}